// Round 12
// baseline (290.580 us; speedup 1.0000x reference)
//
#include <hip/hip_runtime.h>
#include <hip/hip_bf16.h>
#include <math.h>

#define NN 50000
#define NE 800000
#define IN_CH 256
#define HEADS 4
#define OUT_CH 32
#define HC 128            // HEADS*OUT_CH
#define NEG_SLOPE 0.2f
#define GAT_EPS 1e-16f
#define NEG_BIG -1e30f

// parallel scan geometry (node hist scan)
#define SBS 1024
#define NB  ((NN + SBS - 1) / SBS)   // 49

// binned scatter geometry
#define NBINS 64          // allocated bins (49 used)
#define BINSH 10          // bin = dst >> 10 (1024 nodes/bin)
#define NBBIN 49          // ceil(NN/1024)
#define NBLK  625         // edge blocks
#define EPB   1280        // 625*1280 = 800000 exactly (5 iters x 256 thr)

// workspace layout, in 4-byte units
#define OFF_HB     0                          // NN*HC bf16
#define OFF_WT     (NN*HC/2)                  // 128*256 bf16
#define OFF_AI     (OFF_WT + 16384)
#define OFF_AJ     (OFF_AI + NN*HEADS)
#define OFF_ROW    (OFF_AJ + NN*HEADS)        // NN+1 ints
#define OFF_CUR    (OFF_ROW + NN + 4)
#define OFF_HIST   (OFF_CUR + NN + 4)
#define OFF_BSUM   (OFF_HIST + NN + 4)
#define OFF_BOFF   (OFF_BSUM + NB + 4)
#define OFF_BLKC   (OFF_BOFF + NB + 4)        // NBLK*NBINS ints
#define OFF_BLKO   (OFF_BLKC + NBLK*NBINS)    // NBLK*NBINS ints
#define OFF_PAIR   ((OFF_BLKO + NBLK*NBINS + 1) & ~1)  // NE int2 (8B aligned)
#define OFF_ESRC   (OFF_PAIR + 2*NE)          // NE ints

typedef __attribute__((ext_vector_type(8))) short short8v;   // 8 bf16
typedef __attribute__((ext_vector_type(4))) float float4v;

__device__ __forceinline__ unsigned short f2bf(float x) {
    union { float f; unsigned u; } v; v.f = x;
    unsigned r = v.u + 0x7fffu + ((v.u >> 16) & 1u);   // RNE
    return (unsigned short)(r >> 16);
}
__device__ __forceinline__ float bf2f_lo(unsigned u) {
    union { unsigned u; float f; } v; v.u = u << 16;
    return v.f;
}
__device__ __forceinline__ float bf2f_hi(unsigned u) {
    union { unsigned u; float f; } v; v.u = u & 0xffff0000u;
    return v.f;
}

// fused: zero hist + transpose W to bf16 Wt[128][256]
__global__ void k_init(int* __restrict__ hist, const float* __restrict__ W,
                       unsigned short* __restrict__ Wt) {
    int idx = blockIdx.x * blockDim.x + threadIdx.x;
    if (idx < NN) hist[idx] = 0;
    if (idx < HC * IN_CH) {
        int n = idx >> 8, k = idx & 255;
        Wt[n * IN_CH + k] = f2bf(W[(size_t)k * HC + n]);
    }
}

// MFMA bf16 GEMM: Hb[n][c] = bf16( sum_k A[n][k]*W[k][c] )
__global__ __launch_bounds__(256) void k_gemm(const float* __restrict__ A,
                                              const unsigned short* __restrict__ Wt,
                                              unsigned short* __restrict__ Hb) {
    const int tid  = threadIdx.x;
    const int lane = tid & 63;
    const int w    = tid >> 6;
    const int wr   = w >> 1, wc = w & 1;
    const int blockRow = blockIdx.x * 128;

    const int lrow = lane & 15;
    const int kgrp = lane >> 4;

    float4v acc[4][4];
#pragma unroll
    for (int i = 0; i < 4; i++)
#pragma unroll
        for (int j = 0; j < 4; j++) acc[i][j] = (float4v){0.f, 0.f, 0.f, 0.f};

#pragma unroll
    for (int ks = 0; ks < 8; ks++) {
        const int kb = ks * 32 + kgrp * 8;
        short8v af[4], bfr[4];
#pragma unroll
        for (int mi = 0; mi < 4; mi++) {
            int r = blockRow + wr * 64 + mi * 16 + lrow;
            if (r >= NN) r = NN - 1;
            const float* ap = A + (size_t)r * IN_CH + kb;
            float4 a0 = *(const float4*)ap;
            float4 a1 = *(const float4*)(ap + 4);
            short8v t;
            t[0] = (short)f2bf(a0.x); t[1] = (short)f2bf(a0.y);
            t[2] = (short)f2bf(a0.z); t[3] = (short)f2bf(a0.w);
            t[4] = (short)f2bf(a1.x); t[5] = (short)f2bf(a1.y);
            t[6] = (short)f2bf(a1.z); t[7] = (short)f2bf(a1.w);
            af[mi] = t;
        }
#pragma unroll
        for (int ni = 0; ni < 4; ni++) {
            int c = wc * 64 + ni * 16 + lrow;
            bfr[ni] = *(const short8v*)(Wt + (size_t)c * IN_CH + kb);
        }
#pragma unroll
        for (int mi = 0; mi < 4; mi++)
#pragma unroll
            for (int ni = 0; ni < 4; ni++)
                acc[mi][ni] = __builtin_amdgcn_mfma_f32_16x16x32_bf16(
                    af[mi], bfr[ni], acc[mi][ni], 0, 0, 0);
    }

#pragma unroll
    for (int mi = 0; mi < 4; mi++) {
#pragma unroll
        for (int reg = 0; reg < 4; reg++) {
            int r = blockRow + wr * 64 + mi * 16 + kgrp * 4 + reg;
            if (r >= NN) continue;
#pragma unroll
            for (int ni = 0; ni < 4; ni++) {
                int c = wc * 64 + ni * 16 + lrow;
                Hb[(size_t)r * HC + c] = f2bf(acc[mi][ni][reg]);
            }
        }
    }
}

// per-(node,head) attention dots from bf16 h
__global__ void k_att(const unsigned short* __restrict__ Hb, const float* __restrict__ att,
                      float* __restrict__ ai, float* __restrict__ aj) {
    int idx = blockIdx.x * blockDim.x + threadIdx.x;
    if (idx >= NN * HEADS) return;
    int n = idx >> 2, hh = idx & 3;
    const unsigned* hp = (const unsigned*)(Hb + (size_t)n * HC + hh * OUT_CH);
    const float* ati = att + hh * 2 * OUT_CH;
    const float* atj = ati + OUT_CH;
    float si = 0.f, sj = 0.f;
#pragma unroll
    for (int i = 0; i < 16; i++) {
        unsigned u = hp[i];
        float lo = bf2f_lo(u);
        float hi = bf2f_hi(u);
        si = fmaf(lo, ati[2 * i], si);     si = fmaf(hi, ati[2 * i + 1], si);
        sj = fmaf(lo, atj[2 * i], sj);     sj = fmaf(hi, atj[2 * i + 1], sj);
    }
    ai[idx] = si;
    aj[idx] = sj;
}

// binned scatter phase 1: node histogram + per-block bin counts
__global__ __launch_bounds__(256) void s_count(const int* __restrict__ adj,
                                               int* __restrict__ hist,
                                               int* __restrict__ blkcnt) {
    __shared__ int lh[NBINS];
    int b = blockIdx.x, t = threadIdx.x;
    if (t < NBINS) lh[t] = 0;
    __syncthreads();
    int e0 = b * EPB;
#pragma unroll
    for (int i = 0; i < 5; i++) {
        int e = e0 + i * 256 + t;
        int dst = adj[e];
        atomicAdd(&hist[dst], 1);
        atomicAdd(&lh[dst >> BINSH], 1);
    }
    __syncthreads();
    if (t < NBINS) blkcnt[b * NBINS + t] = lh[t];
}

// binned scatter phase 2: per-bin exclusive scan over the 625 block counts
__global__ __launch_bounds__(640) void s_scanblk(const int* __restrict__ blkcnt,
                                                 int* __restrict__ blkoff) {
    int bin = blockIdx.x, t = threadIdx.x;
    int c = (t < NBLK) ? blkcnt[t * NBINS + bin] : 0;
    int lane = t & 63, w = t >> 6;
    int inc = c;
#pragma unroll
    for (int off = 1; off < 64; off <<= 1) {
        int u = __shfl_up(inc, off);
        if (lane >= off) inc += u;
    }
    __shared__ int wsum[10];
    if (lane == 63) wsum[w] = inc;
    __syncthreads();
    int wpre = 0;
    for (int i = 0; i < w; i++) wpre += wsum[i];
    if (t < NBLK) blkoff[t * NBINS + bin] = wpre + inc - c;   // exclusive
}

// binned scatter phase 3: write (dst,src) pairs, bin-grouped, coalesced runs
__global__ __launch_bounds__(256) void s_pairs(const int* __restrict__ adj,
                                               const int* __restrict__ rowp,
                                               const int* __restrict__ blkoff,
                                               int2* __restrict__ paired) {
    __shared__ int lh[NBINS];
    __shared__ int base[NBINS];
    int b = blockIdx.x, t = threadIdx.x;
    if (t < NBINS) {
        lh[t] = 0;
        int n0 = t << BINSH;
        base[t] = rowp[n0 < NN ? n0 : NN] + blkoff[b * NBINS + t];
    }
    __syncthreads();
    int e0 = b * EPB;
#pragma unroll
    for (int i = 0; i < 5; i++) {
        int e = e0 + i * 256 + t;
        int dst = adj[e];
        int src = adj[NE + e];
        int bin = dst >> BINSH;
        int r = atomicAdd(&lh[bin], 1);
        paired[base[bin] + r] = make_int2(dst, src);
    }
}

// binned scatter phase 4: exact CSR within each bin's contiguous window
__global__ __launch_bounds__(256) void s_csr(const int2* __restrict__ paired,
                                             const int* __restrict__ rowp,
                                             int* __restrict__ esrc) {
    __shared__ int cur2[1 << BINSH];
    int b = blockIdx.x, t = threadIdx.x;
    for (int i = t; i < (1 << BINSH); i += 256) cur2[i] = 0;
    __syncthreads();
    int n0 = b << BINSH;
    int n1 = n0 + (1 << BINSH); if (n1 > NN) n1 = NN;
    int e0 = rowp[n0], e1 = rowp[n1];
    for (int i = e0 + t; i < e1; i += 256) {
        int2 p = paired[i];
        int off = atomicAdd(&cur2[p.x - n0], 1);
        esrc[rowp[p.x] + off] = p.y;
    }
}

// scan A: per-block (1024 elems) sum -> bsum[NB]
__global__ __launch_bounds__(256) void k_bsum(const int* __restrict__ hist,
                                              int* __restrict__ bsum) {
    int b = blockIdx.x, t = threadIdx.x;
    int i0 = b * SBS + t * 4;
    int s = 0;
#pragma unroll
    for (int j = 0; j < 4; j++) {
        int i = i0 + j;
        if (i < NN) s += hist[i];
    }
#pragma unroll
    for (int off = 32; off; off >>= 1) s += __shfl_xor(s, off);
    __shared__ int ws[4];
    int lane = t & 63, wid = t >> 6;
    if (lane == 0) ws[wid] = s;
    __syncthreads();
    if (t == 0) bsum[b] = ws[0] + ws[1] + ws[2] + ws[3];
}

// scan B: one wave exclusive-scans bsum
__global__ __launch_bounds__(64) void k_bscan(const int* __restrict__ bsum,
                                              int* __restrict__ boff) {
    int lane = threadIdx.x;
    int v = (lane < NB) ? bsum[lane] : 0;
    int inc = v;
#pragma unroll
    for (int off = 1; off < 64; off <<= 1) {
        int u = __shfl_up(inc, off);
        if (lane >= off) inc += u;
    }
    if (lane < NB) boff[lane] = inc - v;
}

// scan C: block-local exclusive scan + block offset -> row; row[NN]=NE
__global__ __launch_bounds__(256) void k_bwrite(const int* __restrict__ hist,
                                                const int* __restrict__ boff,
                                                int* __restrict__ row,
                                                int* __restrict__ cur) {
    int b = blockIdx.x, t = threadIdx.x;
    int i0 = b * SBS + t * 4;
    int v[4];
    int s = 0;
#pragma unroll
    for (int j = 0; j < 4; j++) {
        int i = i0 + j;
        v[j] = (i < NN) ? hist[i] : 0;
        s += v[j];
    }
    int lane = t & 63, wid = t >> 6;
    int inc = s;
#pragma unroll
    for (int off = 1; off < 64; off <<= 1) {
        int u = __shfl_up(inc, off);
        if (lane >= off) inc += u;
    }
    __shared__ int wsum[4];
    if (lane == 63) wsum[wid] = inc;
    __syncthreads();
    int woff = 0;
    for (int w2 = 0; w2 < wid; w2++) woff += wsum[w2];
    int run = boff[b] + woff + (inc - s);
#pragma unroll
    for (int j = 0; j < 4; j++) {
        int i = i0 + j;
        if (i < NN) {
            row[i] = run;
            cur[i] = run;
            run += v[j];
        }
    }
    if (b == 0 && t == 0) row[NN] = NE;
}

__device__ __forceinline__ float lrelu(float x) {
    return x > 0.f ? x : NEG_SLOPE * x;
}

// one wave per node: online softmax (1 sweep) + chunked shuffle aggregation
__global__ __launch_bounds__(256) void k_gather(const int* __restrict__ row,
                                                const int* __restrict__ esrc,
                                                const float* __restrict__ ai,
                                                const float* __restrict__ aj,
                                                const unsigned short* __restrict__ Hb,
                                                const float* __restrict__ bias,
                                                float* __restrict__ out) {
    int gid = blockIdx.x * blockDim.x + threadIdx.x;
    int nid = gid >> 6;
    int lane = gid & 63;
    if (nid >= NN) return;
    int r0 = row[nid];
    int deg = row[nid + 1] - r0;

    float4 aiv = *(const float4*)&ai[nid * 4];

    // online softmax: single sweep computing running (max, sum) per head
    float m0 = NEG_BIG, m1 = NEG_BIG, m2 = NEG_BIG, m3 = NEG_BIG;
    float s0 = 0.f, s1 = 0.f, s2 = 0.f, s3 = 0.f;
    for (int k = lane; k < deg; k += 64) {
        int s = esrc[r0 + k];
        float4 ajv = *(const float4*)&aj[s * 4];
        float a0 = lrelu(aiv.x + ajv.x);
        float a1 = lrelu(aiv.y + ajv.y);
        float a2 = lrelu(aiv.z + ajv.z);
        float a3 = lrelu(aiv.w + ajv.w);
        float n0 = fmaxf(m0, a0); s0 = s0 * __expf(m0 - n0) + __expf(a0 - n0); m0 = n0;
        float n1 = fmaxf(m1, a1); s1 = s1 * __expf(m1 - n1) + __expf(a1 - n1); m1 = n1;
        float n2 = fmaxf(m2, a2); s2 = s2 * __expf(m2 - n2) + __expf(a2 - n2); m2 = n2;
        float n3 = fmaxf(m3, a3); s3 = s3 * __expf(m3 - n3) + __expf(a3 - n3); m3 = n3;
    }
    // cross-lane merge of (m,s) pairs
#pragma unroll
    for (int off = 32; off; off >>= 1) {
        float om, os, nm;
        om = __shfl_xor(m0, off); os = __shfl_xor(s0, off);
        nm = fmaxf(m0, om); s0 = s0 * __expf(m0 - nm) + os * __expf(om - nm); m0 = nm;
        om = __shfl_xor(m1, off); os = __shfl_xor(s1, off);
        nm = fmaxf(m1, om); s1 = s1 * __expf(m1 - nm) + os * __expf(om - nm); m1 = nm;
        om = __shfl_xor(m2, off); os = __shfl_xor(s2, off);
        nm = fmaxf(m2, om); s2 = s2 * __expf(m2 - nm) + os * __expf(om - nm); m2 = nm;
        om = __shfl_xor(m3, off); os = __shfl_xor(s3, off);
        nm = fmaxf(m3, om); s3 = s3 * __expf(m3 - nm) + os * __expf(om - nm); m3 = nm;
    }

    // per-lane head selection; lane owns channels c0,c0+1 of head hh
    int c0 = lane * 2;
    int hh = lane >> 4;
    float mh  = (hh & 2) ? ((hh & 1) ? m3 : m2) : ((hh & 1) ? m1 : m0);
    float sh  = (hh & 2) ? ((hh & 1) ? s3 : s2) : ((hh & 1) ? s1 : s0);
    float aih = (hh & 2) ? ((hh & 1) ? aiv.w : aiv.z) : ((hh & 1) ? aiv.y : aiv.x);
    float inv = 1.0f / (sh + GAT_EPS);

    // chunked aggregation: 16 edges/chunk; lane (e=lane&15, h=hh) computes a once
    float accx = 0.f, accy = 0.f;
    int ec = lane & 15;
    for (int kc = 0; kc < deg; kc += 16) {
        int nk = deg - kc; if (nk > 16) nk = 16;
        int sv = 0; float av = 0.f;
        if (ec < nk) {
            sv = esrc[r0 + kc + ec];
            float ajv = aj[sv * 4 + hh];
            float al = lrelu(aih + ajv);
            av = __expf(al - mh) * inv;
        }
#pragma unroll 4
        for (int k = 0; k < nk; k++) {
            int s = __shfl(sv, k);                       // lane k (head-0 group)
            float a = __shfl(av, (hh << 4) | k);         // same edge, own head
            unsigned hu = *(const unsigned*)(Hb + (size_t)s * HC + c0);
            accx = fmaf(bf2f_lo(hu), a, accx);
            accy = fmaf(bf2f_hi(hu), a, accy);
        }
    }
    out[(size_t)nid * HC + c0]     = accx + bias[c0];
    out[(size_t)nid * HC + c0 + 1] = accy + bias[c0 + 1];
}

extern "C" void kernel_launch(void* const* d_in, const int* in_sizes, int n_in,
                              void* d_out, int out_size, void* d_ws, size_t ws_size,
                              hipStream_t stream) {
    const float* nodes  = (const float*)d_in[0];
    const int*   adj    = (const int*)d_in[1];
    const float* weight = (const float*)d_in[2];
    const float* att    = (const float*)d_in[3];
    const float* bias   = (const float*)d_in[4];
    float* out = (float*)d_out;
    float* ws  = (float*)d_ws;

    unsigned short* Hb = (unsigned short*)(ws + OFF_HB);
    unsigned short* Wt = (unsigned short*)(ws + OFF_WT);
    float* ai    = ws + OFF_AI;
    float* aj    = ws + OFF_AJ;
    int*   rowp  = (int*)(ws + OFF_ROW);
    int*   cur   = (int*)(ws + OFF_CUR);
    int*   hist  = (int*)(ws + OFF_HIST);
    int*   bsum  = (int*)(ws + OFF_BSUM);
    int*   boff  = (int*)(ws + OFF_BOFF);
    int*   blkc  = (int*)(ws + OFF_BLKC);
    int*   blko  = (int*)(ws + OFF_BLKO);
    int2*  pair  = (int2*)(ws + OFF_PAIR);
    int*   esrc  = (int*)(ws + OFF_ESRC);

    k_init<<<(NN + 255) / 256, 256, 0, stream>>>(hist, weight, Wt);
    s_count<<<NBLK, 256, 0, stream>>>(adj, hist, blkc);
    k_bsum<<<NB, 256, 0, stream>>>(hist, bsum);
    k_bscan<<<1, 64, 0, stream>>>(bsum, boff);
    k_bwrite<<<NB, 256, 0, stream>>>(hist, boff, rowp, cur);
    s_scanblk<<<NBINS, 640, 0, stream>>>(blkc, blko);
    s_pairs<<<NBLK, 256, 0, stream>>>(adj, rowp, blko, pair);
    s_csr<<<NBBIN, 256, 0, stream>>>(pair, rowp, esrc);
    k_gemm<<<(NN + 127) / 128, 256, 0, stream>>>(nodes, Wt, Hb);
    k_att<<<(NN * HEADS + 255) / 256, 256, 0, stream>>>(Hb, att, ai, aj);
    k_gather<<<(NN * 64 + 255) / 256, 256, 0, stream>>>(rowp, esrc, ai, aj, Hb, bias, out);
}

// Round 13
// 288.173 us; speedup vs baseline: 1.0084x; 1.0084x over previous
//
#include <hip/hip_runtime.h>
#include <hip/hip_bf16.h>
#include <math.h>

#define NN 50000
#define NE 800000
#define IN_CH 256
#define HEADS 4
#define OUT_CH 32
#define HC 128            // HEADS*OUT_CH
#define NEG_SLOPE 0.2f
#define GAT_EPS 1e-16f

// parallel scan geometry (node hist scan)
#define SBS 1024
#define NB  ((NN + SBS - 1) / SBS)   // 49

// binned scatter geometry
#define NBINS 64          // allocated bins (49 used)
#define BINSH 10          // bin = dst >> 10 (1024 nodes/bin)
#define NBBIN 49          // ceil(NN/1024)
#define NBLK  625         // edge blocks
#define EPB   1280        // 625*1280 = 800000 exactly (5 iters x 256 thr)

// workspace layout, in 4-byte units
#define OFF_HB     0                          // NN*HC bf16
#define OFF_WT     (NN*HC/2)                  // 128*256 bf16
#define OFF_AI     (OFF_WT + 16384)
#define OFF_AJ     (OFF_AI + NN*HEADS)
#define OFF_ROW    (OFF_AJ + NN*HEADS)        // NN+1 ints
#define OFF_HIST   (OFF_ROW + NN + 4)
#define OFF_BSUM   (OFF_HIST + NN + 4)
#define OFF_BLKC   (OFF_BSUM + NB + 4)        // NBLK*NBINS ints
#define OFF_BLKO   (OFF_BLKC + NBLK*NBINS)    // NBLK*NBINS ints
#define OFF_PAIR   ((OFF_BLKO + NBLK*NBINS + 1) & ~1)  // NE int2 (8B aligned)
#define OFF_ESRC   (OFF_PAIR + 2*NE)          // NE ints

typedef __attribute__((ext_vector_type(8))) short short8v;   // 8 bf16
typedef __attribute__((ext_vector_type(4))) float float4v;

__device__ __forceinline__ unsigned short f2bf(float x) {
    union { float f; unsigned u; } v; v.f = x;
    unsigned r = v.u + 0x7fffu + ((v.u >> 16) & 1u);   // RNE
    return (unsigned short)(r >> 16);
}
__device__ __forceinline__ float bf2f_lo(unsigned u) {
    union { unsigned u; float f; } v; v.u = u << 16;
    return v.f;
}
__device__ __forceinline__ float bf2f_hi(unsigned u) {
    union { unsigned u; float f; } v; v.u = u & 0xffff0000u;
    return v.f;
}

// fused: zero hist + transpose W to bf16 Wt[128][256]
__global__ void k_init(int* __restrict__ hist, const float* __restrict__ W,
                       unsigned short* __restrict__ Wt) {
    int idx = blockIdx.x * blockDim.x + threadIdx.x;
    if (idx < NN) hist[idx] = 0;
    if (idx < HC * IN_CH) {
        int n = idx >> 8, k = idx & 255;
        Wt[n * IN_CH + k] = f2bf(W[(size_t)k * HC + n]);
    }
}

// MFMA bf16 GEMM: Hb[n][c] = bf16( sum_k A[n][k]*W[k][c] )
__global__ __launch_bounds__(256) void k_gemm(const float* __restrict__ A,
                                              const unsigned short* __restrict__ Wt,
                                              unsigned short* __restrict__ Hb) {
    const int tid  = threadIdx.x;
    const int lane = tid & 63;
    const int w    = tid >> 6;
    const int wr   = w >> 1, wc = w & 1;
    const int blockRow = blockIdx.x * 128;

    const int lrow = lane & 15;
    const int kgrp = lane >> 4;

    float4v acc[4][4];
#pragma unroll
    for (int i = 0; i < 4; i++)
#pragma unroll
        for (int j = 0; j < 4; j++) acc[i][j] = (float4v){0.f, 0.f, 0.f, 0.f};

#pragma unroll
    for (int ks = 0; ks < 8; ks++) {
        const int kb = ks * 32 + kgrp * 8;
        short8v af[4], bfr[4];
#pragma unroll
        for (int mi = 0; mi < 4; mi++) {
            int r = blockRow + wr * 64 + mi * 16 + lrow;
            if (r >= NN) r = NN - 1;
            const float* ap = A + (size_t)r * IN_CH + kb;
            float4 a0 = *(const float4*)ap;
            float4 a1 = *(const float4*)(ap + 4);
            short8v t;
            t[0] = (short)f2bf(a0.x); t[1] = (short)f2bf(a0.y);
            t[2] = (short)f2bf(a0.z); t[3] = (short)f2bf(a0.w);
            t[4] = (short)f2bf(a1.x); t[5] = (short)f2bf(a1.y);
            t[6] = (short)f2bf(a1.z); t[7] = (short)f2bf(a1.w);
            af[mi] = t;
        }
#pragma unroll
        for (int ni = 0; ni < 4; ni++) {
            int c = wc * 64 + ni * 16 + lrow;
            bfr[ni] = *(const short8v*)(Wt + (size_t)c * IN_CH + kb);
        }
#pragma unroll
        for (int mi = 0; mi < 4; mi++)
#pragma unroll
            for (int ni = 0; ni < 4; ni++)
                acc[mi][ni] = __builtin_amdgcn_mfma_f32_16x16x32_bf16(
                    af[mi], bfr[ni], acc[mi][ni], 0, 0, 0);
    }

#pragma unroll
    for (int mi = 0; mi < 4; mi++) {
#pragma unroll
        for (int reg = 0; reg < 4; reg++) {
            int r = blockRow + wr * 64 + mi * 16 + kgrp * 4 + reg;
            if (r >= NN) continue;
#pragma unroll
            for (int ni = 0; ni < 4; ni++) {
                int c = wc * 64 + ni * 16 + lrow;
                Hb[(size_t)r * HC + c] = f2bf(acc[mi][ni][reg]);
            }
        }
    }
}

// per-(node,head) attention dots from bf16 h
__global__ void k_att(const unsigned short* __restrict__ Hb, const float* __restrict__ att,
                      float* __restrict__ ai, float* __restrict__ aj) {
    int idx = blockIdx.x * blockDim.x + threadIdx.x;
    if (idx >= NN * HEADS) return;
    int n = idx >> 2, hh = idx & 3;
    const unsigned* hp = (const unsigned*)(Hb + (size_t)n * HC + hh * OUT_CH);
    const float* ati = att + hh * 2 * OUT_CH;
    const float* atj = ati + OUT_CH;
    float si = 0.f, sj = 0.f;
#pragma unroll
    for (int i = 0; i < 16; i++) {
        unsigned u = hp[i];
        float lo = bf2f_lo(u);
        float hi = bf2f_hi(u);
        si = fmaf(lo, ati[2 * i], si);     si = fmaf(hi, ati[2 * i + 1], si);
        sj = fmaf(lo, atj[2 * i], sj);     sj = fmaf(hi, atj[2 * i + 1], sj);
    }
    ai[idx] = si;
    aj[idx] = sj;
}

// binned scatter phase 1: node histogram + per-block bin counts
__global__ __launch_bounds__(256) void s_count(const int* __restrict__ adj,
                                               int* __restrict__ hist,
                                               int* __restrict__ blkcnt) {
    __shared__ int lh[NBINS];
    int b = blockIdx.x, t = threadIdx.x;
    if (t < NBINS) lh[t] = 0;
    __syncthreads();
    int e0 = b * EPB;
#pragma unroll
    for (int i = 0; i < 5; i++) {
        int e = e0 + i * 256 + t;
        int dst = adj[e];
        atomicAdd(&hist[dst], 1);
        atomicAdd(&lh[dst >> BINSH], 1);
    }
    __syncthreads();
    if (t < NBINS) blkcnt[b * NBINS + t] = lh[t];
}

// binned scatter phase 2: per-bin exclusive scan over the 625 block counts
__global__ __launch_bounds__(640) void s_scanblk(const int* __restrict__ blkcnt,
                                                 int* __restrict__ blkoff) {
    int bin = blockIdx.x, t = threadIdx.x;
    int c = (t < NBLK) ? blkcnt[t * NBINS + bin] : 0;
    int lane = t & 63, w = t >> 6;
    int inc = c;
#pragma unroll
    for (int off = 1; off < 64; off <<= 1) {
        int u = __shfl_up(inc, off);
        if (lane >= off) inc += u;
    }
    __shared__ int wsum[10];
    if (lane == 63) wsum[w] = inc;
    __syncthreads();
    int wpre = 0;
    for (int i = 0; i < w; i++) wpre += wsum[i];
    if (t < NBLK) blkoff[t * NBINS + bin] = wpre + inc - c;   // exclusive
}

// binned scatter phase 3: write (dst,src) pairs, bin-grouped, coalesced runs
__global__ __launch_bounds__(256) void s_pairs(const int* __restrict__ adj,
                                               const int* __restrict__ rowp,
                                               const int* __restrict__ blkoff,
                                               int2* __restrict__ paired) {
    __shared__ int lh[NBINS];
    __shared__ int base[NBINS];
    int b = blockIdx.x, t = threadIdx.x;
    if (t < NBINS) {
        lh[t] = 0;
        int n0 = t << BINSH;
        base[t] = rowp[n0 < NN ? n0 : NN] + blkoff[b * NBINS + t];
    }
    __syncthreads();
    int e0 = b * EPB;
#pragma unroll
    for (int i = 0; i < 5; i++) {
        int e = e0 + i * 256 + t;
        int dst = adj[e];
        int src = adj[NE + e];
        int bin = dst >> BINSH;
        int r = atomicAdd(&lh[bin], 1);
        paired[base[bin] + r] = make_int2(dst, src);
    }
}

// binned scatter phase 4: exact CSR within each bin's contiguous window
__global__ __launch_bounds__(256) void s_csr(const int2* __restrict__ paired,
                                             const int* __restrict__ rowp,
                                             int* __restrict__ esrc) {
    __shared__ int cur2[1 << BINSH];
    int b = blockIdx.x, t = threadIdx.x;
    for (int i = t; i < (1 << BINSH); i += 256) cur2[i] = 0;
    __syncthreads();
    int n0 = b << BINSH;
    int n1 = n0 + (1 << BINSH); if (n1 > NN) n1 = NN;
    int e0 = rowp[n0], e1 = rowp[n1];
    for (int i = e0 + t; i < e1; i += 256) {
        int2 p = paired[i];
        int off = atomicAdd(&cur2[p.x - n0], 1);
        esrc[rowp[p.x] + off] = p.y;
    }
}

// scan A: per-block (1024 elems) sum -> bsum[NB]
__global__ __launch_bounds__(256) void k_bsum(const int* __restrict__ hist,
                                              int* __restrict__ bsum) {
    int b = blockIdx.x, t = threadIdx.x;
    int i0 = b * SBS + t * 4;
    int s = 0;
#pragma unroll
    for (int j = 0; j < 4; j++) {
        int i = i0 + j;
        if (i < NN) s += hist[i];
    }
#pragma unroll
    for (int off = 32; off; off >>= 1) s += __shfl_xor(s, off);
    __shared__ int ws[4];
    int lane = t & 63, wid = t >> 6;
    if (lane == 0) ws[wid] = s;
    __syncthreads();
    if (t == 0) bsum[b] = ws[0] + ws[1] + ws[2] + ws[3];
}

// scan C (with inline block-offset): block-local exclusive scan -> row; row[NN]=NE
__global__ __launch_bounds__(256) void k_bwrite(const int* __restrict__ hist,
                                                const int* __restrict__ bsum,
                                                int* __restrict__ row) {
    __shared__ int s_boff;
    int b = blockIdx.x, t = threadIdx.x;
    // inline scan of bsum[0..b-1] by wave 0
    if (t < 64) {
        int v = (t < b) ? bsum[t] : 0;          // b <= 48 < 64
#pragma unroll
        for (int off = 32; off; off >>= 1) v += __shfl_xor(v, off);
        if (t == 0) s_boff = v;
    }
    __syncthreads();
    int i0 = b * SBS + t * 4;
    int v[4];
    int s = 0;
#pragma unroll
    for (int j = 0; j < 4; j++) {
        int i = i0 + j;
        v[j] = (i < NN) ? hist[i] : 0;
        s += v[j];
    }
    int lane = t & 63, wid = t >> 6;
    int inc = s;
#pragma unroll
    for (int off = 1; off < 64; off <<= 1) {
        int u = __shfl_up(inc, off);
        if (lane >= off) inc += u;
    }
    __shared__ int wsum[4];
    if (lane == 63) wsum[wid] = inc;
    __syncthreads();
    int woff = 0;
    for (int w2 = 0; w2 < wid; w2++) woff += wsum[w2];
    int run = s_boff + woff + (inc - s);
#pragma unroll
    for (int j = 0; j < 4; j++) {
        int i = i0 + j;
        if (i < NN) {
            row[i] = run;
            run += v[j];
        }
    }
    if (b == 0 && t == 0) row[NN] = NE;
}

__device__ __forceinline__ float lrelu(float x) {
    return x > 0.f ? x : NEG_SLOPE * x;
}

// one wave per node: max sweep + fused unnormalized-weighted sweep (2 edges/iter)
__global__ __launch_bounds__(256) void k_gather(const int* __restrict__ row,
                                                const int* __restrict__ esrc,
                                                const float* __restrict__ ai,
                                                const float* __restrict__ aj,
                                                const unsigned short* __restrict__ Hb,
                                                const float* __restrict__ bias,
                                                float* __restrict__ out) {
    int gid = blockIdx.x * blockDim.x + threadIdx.x;
    int nid = gid >> 6;
    int lane = gid & 63;
    if (nid >= NN) return;
    int r0 = row[nid];
    int deg = row[nid + 1] - r0;

    float4 aiv = *(const float4*)&ai[nid * 4];

    // pass 1: per-head max over incoming edges (strided, then wave reduce)
    float mx0 = -INFINITY, mx1 = -INFINITY, mx2 = -INFINITY, mx3 = -INFINITY;
    for (int k = lane; k < deg; k += 64) {
        int s = esrc[r0 + k];
        float4 ajv = *(const float4*)&aj[s * 4];
        mx0 = fmaxf(mx0, lrelu(aiv.x + ajv.x));
        mx1 = fmaxf(mx1, lrelu(aiv.y + ajv.y));
        mx2 = fmaxf(mx2, lrelu(aiv.z + ajv.z));
        mx3 = fmaxf(mx3, lrelu(aiv.w + ajv.w));
    }
#pragma unroll
    for (int off = 32; off; off >>= 1) {
        mx0 = fmaxf(mx0, __shfl_xor(mx0, off));
        mx1 = fmaxf(mx1, __shfl_xor(mx1, off));
        mx2 = fmaxf(mx2, __shfl_xor(mx2, off));
        mx3 = fmaxf(mx3, __shfl_xor(mx3, off));
    }

    // pass 2 (fused): unnormalized accumulate, 2 edges/iter.
    // half-wave ec2 = lane>>5 takes edge kc+ec2; lane covers 4 channels c0..c0+3
    int cl = lane & 31;
    int c0 = cl * 4;
    int hh = cl >> 3;
    float mh  = (hh & 2) ? ((hh & 1) ? mx3 : mx2) : ((hh & 1) ? mx1 : mx0);
    float aih = (hh & 2) ? ((hh & 1) ? aiv.w : aiv.z) : ((hh & 1) ? aiv.y : aiv.x);

    float ax = 0.f, ay = 0.f, az = 0.f, aw = 0.f;
    float asum = 0.f;
    int ec2 = lane >> 5;
    for (int kc = 0; kc < deg; kc += 2) {
        int k = kc + ec2;
        int s = 0;
        float av = 0.f;
        if (k < deg) {
            s = esrc[r0 + k];                        // 32-lane broadcast
            av = __expf(lrelu(aih + aj[s * 4 + hh]) - mh);
        }
        asum += av;
        uint2 hu = *(const uint2*)(Hb + (size_t)s * HC + c0);   // 8B/lane
        ax = fmaf(bf2f_lo(hu.x), av, ax);
        ay = fmaf(bf2f_hi(hu.x), av, ay);
        az = fmaf(bf2f_lo(hu.y), av, az);
        aw = fmaf(bf2f_hi(hu.y), av, aw);
    }
    // merge the two half-waves
    ax += __shfl_xor(ax, 32);
    ay += __shfl_xor(ay, 32);
    az += __shfl_xor(az, 32);
    aw += __shfl_xor(aw, 32);
    asum += __shfl_xor(asum, 32);

    if (lane < 32) {
        float inv = 1.0f / (asum + GAT_EPS);
        float4 bv = *(const float4*)&bias[c0];
        float4 o;
        o.x = fmaf(ax, inv, bv.x);
        o.y = fmaf(ay, inv, bv.y);
        o.z = fmaf(az, inv, bv.z);
        o.w = fmaf(aw, inv, bv.w);
        *(float4*)&out[(size_t)nid * HC + c0] = o;
    }
}

extern "C" void kernel_launch(void* const* d_in, const int* in_sizes, int n_in,
                              void* d_out, int out_size, void* d_ws, size_t ws_size,
                              hipStream_t stream) {
    const float* nodes  = (const float*)d_in[0];
    const int*   adj    = (const int*)d_in[1];
    const float* weight = (const float*)d_in[2];
    const float* att    = (const float*)d_in[3];
    const float* bias   = (const float*)d_in[4];
    float* out = (float*)d_out;
    float* ws  = (float*)d_ws;

    unsigned short* Hb = (unsigned short*)(ws + OFF_HB);
    unsigned short* Wt = (unsigned short*)(ws + OFF_WT);
    float* ai    = ws + OFF_AI;
    float* aj    = ws + OFF_AJ;
    int*   rowp  = (int*)(ws + OFF_ROW);
    int*   hist  = (int*)(ws + OFF_HIST);
    int*   bsum  = (int*)(ws + OFF_BSUM);
    int*   blkc  = (int*)(ws + OFF_BLKC);
    int*   blko  = (int*)(ws + OFF_BLKO);
    int2*  pair  = (int2*)(ws + OFF_PAIR);
    int*   esrc  = (int*)(ws + OFF_ESRC);

    k_init<<<(NN + 255) / 256, 256, 0, stream>>>(hist, weight, Wt);
    s_count<<<NBLK, 256, 0, stream>>>(adj, hist, blkc);
    k_bsum<<<NB, 256, 0, stream>>>(hist, bsum);
    k_bwrite<<<NB, 256, 0, stream>>>(hist, bsum, rowp);
    s_scanblk<<<NBINS, 640, 0, stream>>>(blkc, blko);
    s_pairs<<<NBLK, 256, 0, stream>>>(adj, rowp, blko, pair);
    s_csr<<<NBBIN, 256, 0, stream>>>(pair, rowp, esrc);
    k_gemm<<<(NN + 127) / 128, 256, 0, stream>>>(nodes, Wt, Hb);
    k_att<<<(NN * HEADS + 255) / 256, 256, 0, stream>>>(Hb, att, ai, aj);
    k_gather<<<(NN * 64 + 255) / 256, 256, 0, stream>>>(rowp, esrc, ai, aj, Hb, bias, out);
}